// Round 2
// baseline (372.427 us; speedup 1.0000x reference)
//
#include <hip/hip_runtime.h>

#define BINS 10

// Per-element work: gradient magnitude -> bin, BCE loss, then ONE no-return
// LDS atomic add each into this thread's private 10-slot histogram row.
// ds_add_f32/ds_add_u32 are fire-and-forget (no VGPR result, no lgkmcnt
// dependency) and run on the LDS pipe, off the VALU critical path.
// Each slot is touched only by its owning thread, in program order ->
// summation order is IDENTICAL to the register-accumulator version
// (bit-exact result), but costs 2 LDS ops instead of ~40 VALU ops/element.
__device__ __forceinline__ void accum_elem(float xx, float tt,
                                           float* __restrict__ slot_sum,
                                           unsigned* __restrict__ slot_cnt) {
    float g = fabsf(xx - tt);
    // reference: floor(g * (10 - 1e-4)); identical fp32 ops -> bit-match
    int b = (int)(g * 9.9999f);
    b = b > (BINS - 1) ? (BINS - 1) : b;
    float loss = -(tt * __logf(xx) + (1.0f - tt) * __logf(1.0f - xx));
    atomicAdd(&slot_sum[b], loss);  // ds_add_f32 (no return)
    atomicAdd(&slot_cnt[b], 1u);    // ds_add_u32 (no return)
}

// ATOMIC=false: write per-block partials to psum/pcnt[block*BINS+k].
// ATOMIC=true : atomically accumulate into psum/pcnt[k] (80 B total),
//               used when the workspace can't hold per-block partials.
template <bool ATOMIC>
__global__ __launch_bounds__(256) void ghm_partial(
    const float* __restrict__ x, const float* __restrict__ t,
    float* __restrict__ psum, unsigned* __restrict__ pcnt,
    int n4, long long n_total)
{
    // Per-thread private histogram rows. 256*10*(4+4) = 20480 B exactly ->
    // 8 blocks/CU on 160 KiB LDS = full 32-wave/CU residency.
    __shared__ float s_sum[256 * BINS];
    __shared__ unsigned s_cnt[256 * BINS];

    float* __restrict__ my_sum = &s_sum[threadIdx.x * BINS];
    unsigned* __restrict__ my_cnt = &s_cnt[threadIdx.x * BINS];
#pragma unroll
    for (int k = 0; k < BINS; ++k) { my_sum[k] = 0.0f; my_cnt[k] = 0u; }
    // no barrier needed: each thread reads/writes only its own slots until
    // the cross-wave stage at the end (which has its own barriers).

    const float4* __restrict__ x4 = (const float4*)x;
    const float4* __restrict__ t4 = (const float4*)t;
    int tid = blockIdx.x * blockDim.x + threadIdx.x;
    int stride = gridDim.x * blockDim.x;

    // grid-stride over float4 pairs, 2x unrolled: 64 B of independent loads
    // in flight per lane per iteration before the (now short) VALU chain.
    int i = tid;
    for (; i + stride < n4; i += 2 * stride) {
        float4 xa = x4[i];
        float4 ta = t4[i];
        float4 xb = x4[i + stride];
        float4 tb = t4[i + stride];
        accum_elem(xa.x, ta.x, my_sum, my_cnt);
        accum_elem(xa.y, ta.y, my_sum, my_cnt);
        accum_elem(xa.z, ta.z, my_sum, my_cnt);
        accum_elem(xa.w, ta.w, my_sum, my_cnt);
        accum_elem(xb.x, tb.x, my_sum, my_cnt);
        accum_elem(xb.y, tb.y, my_sum, my_cnt);
        accum_elem(xb.z, tb.z, my_sum, my_cnt);
        accum_elem(xb.w, tb.w, my_sum, my_cnt);
    }
    if (i < n4) {
        float4 xa = x4[i];
        float4 ta = t4[i];
        accum_elem(xa.x, ta.x, my_sum, my_cnt);
        accum_elem(xa.y, ta.y, my_sum, my_cnt);
        accum_elem(xa.z, ta.z, my_sum, my_cnt);
        accum_elem(xa.w, ta.w, my_sum, my_cnt);
    }
    // scalar tail (N not divisible by 4) — handled by low global tids
    long long tail_base = (long long)n4 * 4;
    long long rem = n_total - tail_base;
    if ((long long)tid < rem) {
        accum_elem(x[tail_base + tid], t[tail_base + tid], my_sum, my_cnt);
    }

    // Read back private rows into registers (only own slots -> no barrier).
    float sum[BINS];
    unsigned cnt[BINS];
#pragma unroll
    for (int k = 0; k < BINS; ++k) { sum[k] = my_sum[k]; cnt[k] = my_cnt[k]; }

    // wave(64) shuffle reduction of 10 sums + 10 counts (fixed tree order,
    // identical to previous version -> deterministic, bit-matching)
#pragma unroll
    for (int k = 0; k < BINS; ++k) {
#pragma unroll
        for (int off = 32; off > 0; off >>= 1) {
            sum[k] += __shfl_down(sum[k], off, 64);
            cnt[k] += (unsigned)__shfl_down((int)cnt[k], off, 64);
        }
    }

    // Cross-wave stage: reuse the front of s_sum/s_cnt (barrier-protected)
    // instead of extra smem, keeping LDS at exactly 20480 B.
    int lane = threadIdx.x & 63;
    int wv = threadIdx.x >> 6;
    __syncthreads();  // everyone done reading their own slots
    if (lane == 0) {
#pragma unroll
        for (int k = 0; k < BINS; ++k) {
            s_sum[wv * BINS + k] = sum[k];
            s_cnt[wv * BINS + k] = cnt[k];
        }
    }
    __syncthreads();
    if (threadIdx.x < BINS) {
        float s = 0.0f;
        unsigned c = 0u;
#pragma unroll
        for (int w = 0; w < 4; ++w) {
            s += s_sum[w * BINS + threadIdx.x];
            c += s_cnt[w * BINS + threadIdx.x];
        }
        if (ATOMIC) {
            atomicAdd(&psum[threadIdx.x], s);
            atomicAdd(&pcnt[threadIdx.x], c);
        } else {
            psum[(size_t)blockIdx.x * BINS + threadIdx.x] = s;
            pcnt[(size_t)blockIdx.x * BINS + threadIdx.x] = c;
        }
    }
}

// Zero the 80 B atomic accumulator region (atomic fallback path only).
__global__ void ghm_zero(float* psum, unsigned* pcnt) {
    if (threadIdx.x < BINS) { psum[threadIdx.x] = 0.0f; pcnt[threadIdx.x] = 0u; }
}

// Single-block finalize: reduce per-block partials, compute beta, weighted sum.
__global__ __launch_bounds__(256) void ghm_final(
    const float* __restrict__ psum, const unsigned* __restrict__ pcnt,
    float* __restrict__ out, int nblocks, float Nf)
{
    float sum[BINS];
    unsigned cnt[BINS];
#pragma unroll
    for (int k = 0; k < BINS; ++k) { sum[k] = 0.0f; cnt[k] = 0u; }

    for (int i = threadIdx.x; i < nblocks; i += blockDim.x) {
#pragma unroll
        for (int k = 0; k < BINS; ++k) {
            sum[k] += psum[(size_t)i * BINS + k];
            cnt[k] += pcnt[(size_t)i * BINS + k];
        }
    }

#pragma unroll
    for (int k = 0; k < BINS; ++k) {
#pragma unroll
        for (int off = 32; off > 0; off >>= 1) {
            sum[k] += __shfl_down(sum[k], off, 64);
            cnt[k] += (unsigned)__shfl_down((int)cnt[k], off, 64);
        }
    }

    __shared__ float s_sum[4][BINS];
    __shared__ unsigned s_cnt[4][BINS];
    int lane = threadIdx.x & 63;
    int wv = threadIdx.x >> 6;
    if (lane == 0) {
#pragma unroll
        for (int k = 0; k < BINS; ++k) { s_sum[wv][k] = sum[k]; s_cnt[wv][k] = cnt[k]; }
    }
    __syncthreads();

    if (threadIdx.x == 0) {
        float tot_s[BINS];
        unsigned tot_c[BINS];
#pragma unroll
        for (int k = 0; k < BINS; ++k) {
            float s = 0.0f;
            unsigned c = 0u;
#pragma unroll
            for (int w = 0; w < 4; ++w) { s += s_sum[w][k]; c += s_cnt[w][k]; }
            tot_s[k] = s;
            tot_c[k] = c;
        }
        float nonempty = 0.0f;
#pragma unroll
        for (int k = 0; k < BINS; ++k) nonempty += (tot_c[k] > 0u) ? 1.0f : 0.0f;
        float total = 0.0f;
#pragma unroll
        for (int k = 0; k < BINS; ++k) {
            float gd = (float)tot_c[k] * nonempty;
            gd = gd < 1.0f ? 1.0f : gd;      // clip(gd, 1, None)
            float beta = Nf / gd;
            total += tot_s[k] * beta;
        }
        out[0] = total / Nf;   // mean
    }
}

extern "C" void kernel_launch(void* const* d_in, const int* in_sizes, int n_in,
                              void* d_out, int out_size, void* d_ws, size_t ws_size,
                              hipStream_t stream) {
    const float* x = (const float*)d_in[0];
    const float* t = (const float*)d_in[1];
    float* out = (float*)d_out;

    long long N = (long long)in_sizes[0];
    int n4 = (int)(N / 4);

    // 2048 blocks x 256 thr = 8192 waves = 32 waves/CU on 256 CUs.
    const int nblocks = 2048;
    const size_t per_block = (size_t)BINS * (sizeof(float) + sizeof(unsigned)); // 80 B

    if (ws_size >= (size_t)nblocks * per_block) {
        // Deterministic two-stage reduction (preferred).
        float* psum = (float*)d_ws;
        unsigned* pcnt = (unsigned*)(psum + (size_t)nblocks * BINS);
        ghm_partial<false><<<nblocks, 256, 0, stream>>>(x, t, psum, pcnt, n4, N);
        ghm_final<<<1, 256, 0, stream>>>(psum, pcnt, out, nblocks, (float)N);
    } else {
        // Atomic fallback: 80 B of workspace, 20 device-scope atomics/block.
        float* psum = (float*)d_ws;
        unsigned* pcnt = (unsigned*)(psum + BINS);
        ghm_zero<<<1, 64, 0, stream>>>(psum, pcnt);
        ghm_partial<true><<<nblocks, 256, 0, stream>>>(x, t, psum, pcnt, n4, N);
        ghm_final<<<1, 256, 0, stream>>>(psum, pcnt, out, 1, (float)N);
    }
}

// Round 3
// 328.874 us; speedup vs baseline: 1.1324x; 1.1324x over previous
//
#include <hip/hip_runtime.h>

#define BINS 10

// bin id: reference floor(g * (10 - 1e-4)); identical fp32 ops -> bit-match
__device__ __forceinline__ int bin_of(float xx, float tt) {
    float g = fabsf(xx - tt);
    int b = (int)(g * 9.9999f);
    return b > (BINS - 1) ? (BINS - 1) : b;
}

// ---------------------------------------------------------------------------
// Pass 1: histogram COUNTS only. Per-bin count = popcount(ballot(b==k)):
// 10 wave-wide v_cmp (VALU) + s_bcnt1/s_add on the SALU pipe per 64 elements.
// This removes the per-lane 10-bin predicated ladder entirely (~40 VALU/elem
// in R1 -> ~0.2 VALU/elem here). wc[] is wave-uniform -> lives in SGPRs.
//
// Divergence safety: every divergent region below has a PREFIX active set
// (smaller lane id <=> smaller global index), so lane 0 is active in every
// ballot that counts anything; the published lane-0/uniform wc is complete.
// ---------------------------------------------------------------------------
__device__ __forceinline__ void count_elem(int b, unsigned* __restrict__ wc) {
#pragma unroll
    for (int k = 0; k < BINS; ++k)
        wc[k] += (unsigned)__popcll(__ballot(b == k));
}

template <bool ATOMIC>
__global__ __launch_bounds__(256) void ghm_count(
    const float* __restrict__ x, const float* __restrict__ t,
    unsigned* __restrict__ pcnt, int n4, long long n_total)
{
    unsigned wc[BINS];
#pragma unroll
    for (int k = 0; k < BINS; ++k) wc[k] = 0u;

    const float4* __restrict__ x4 = (const float4*)x;
    const float4* __restrict__ t4 = (const float4*)t;
    int tid = blockIdx.x * blockDim.x + threadIdx.x;
    int stride = gridDim.x * blockDim.x;

    int i = tid;
    for (; i + stride < n4; i += 2 * stride) {
        float4 xa = x4[i];
        float4 ta = t4[i];
        float4 xb = x4[i + stride];
        float4 tb = t4[i + stride];
        count_elem(bin_of(xa.x, ta.x), wc);
        count_elem(bin_of(xa.y, ta.y), wc);
        count_elem(bin_of(xa.z, ta.z), wc);
        count_elem(bin_of(xa.w, ta.w), wc);
        count_elem(bin_of(xb.x, tb.x), wc);
        count_elem(bin_of(xb.y, tb.y), wc);
        count_elem(bin_of(xb.z, tb.z), wc);
        count_elem(bin_of(xb.w, tb.w), wc);
    }
    if (i < n4) {                       // prefix-active divergence: safe
        float4 xa = x4[i];
        float4 ta = t4[i];
        count_elem(bin_of(xa.x, ta.x), wc);
        count_elem(bin_of(xa.y, ta.y), wc);
        count_elem(bin_of(xa.z, ta.z), wc);
        count_elem(bin_of(xa.w, ta.w), wc);
    }
    long long tail_base = (long long)n4 * 4;
    long long rem = n_total - tail_base;
    if ((long long)tid < rem) {         // prefix-active divergence: safe
        count_elem(bin_of(x[tail_base + tid], t[tail_base + tid]), wc);
    }

    // cross-wave: wc is wave-uniform; one store per wave, then 4-way sum.
    __shared__ unsigned s_c[4][BINS];
    int lane = threadIdx.x & 63;
    int wv = threadIdx.x >> 6;
    if (lane == 0) {
#pragma unroll
        for (int k = 0; k < BINS; ++k) s_c[wv][k] = wc[k];
    }
    __syncthreads();
    if (threadIdx.x < BINS) {
        unsigned c = s_c[0][threadIdx.x] + s_c[1][threadIdx.x]
                   + s_c[2][threadIdx.x] + s_c[3][threadIdx.x];
        if (ATOMIC) atomicAdd(&pcnt[threadIdx.x], c);
        else        pcnt[(size_t)blockIdx.x * BINS + threadIdx.x] = c;
    }
}

// ---------------------------------------------------------------------------
// Tiny kernel: reduce per-block counts, compute -beta[k] (negated so pass 2
// can use  p * nbeta  ==  (-(p)) * beta  == loss * beta, bitwise identical).
// ---------------------------------------------------------------------------
__global__ __launch_bounds__(256) void ghm_beta(
    const unsigned* __restrict__ pcnt, float* __restrict__ nbeta,
    int nblocks, float Nf)
{
    unsigned cnt[BINS];
#pragma unroll
    for (int k = 0; k < BINS; ++k) cnt[k] = 0u;

    for (int i = threadIdx.x; i < nblocks; i += blockDim.x) {
#pragma unroll
        for (int k = 0; k < BINS; ++k) cnt[k] += pcnt[(size_t)i * BINS + k];
    }
#pragma unroll
    for (int k = 0; k < BINS; ++k) {
#pragma unroll
        for (int off = 32; off > 0; off >>= 1)
            cnt[k] += (unsigned)__shfl_down((int)cnt[k], off, 64);
    }
    __shared__ unsigned s_c[4][BINS];
    int lane = threadIdx.x & 63;
    int wv = threadIdx.x >> 6;
    if (lane == 0) {
#pragma unroll
        for (int k = 0; k < BINS; ++k) s_c[wv][k] = cnt[k];
    }
    __syncthreads();
    if (threadIdx.x == 0) {
        unsigned tot[BINS];
        float nonempty = 0.0f;
#pragma unroll
        for (int k = 0; k < BINS; ++k) {
            tot[k] = s_c[0][k] + s_c[1][k] + s_c[2][k] + s_c[3][k];
            nonempty += (tot[k] > 0u) ? 1.0f : 0.0f;
        }
#pragma unroll
        for (int k = 0; k < BINS; ++k) {
            float gd = (float)tot[k] * nonempty;
            gd = gd < 1.0f ? 1.0f : gd;      // clip(gd, 1, None)
            nbeta[k] = -(Nf / gd);
        }
    }
}

// ---------------------------------------------------------------------------
// Pass 2: weighted BCE sum. beta gather is ONE ds_read_b32 per element from a
// 10-float LDS table: 10 distinct addresses -> 10 distinct banks, same-address
// lanes broadcast -> conflict-free. Per element ~12 VALU + 2 v_log + 1 LDS;
// memory-bound.
// ---------------------------------------------------------------------------
__device__ __forceinline__ float welem(float xx, float tt,
                                       const float* __restrict__ s_nb) {
    int b = bin_of(xx, tt);
    float p = tt * __logf(xx) + (1.0f - tt) * __logf(1.0f - xx);
    return p * s_nb[b];                  // == loss * beta
}

template <bool ATOMIC>
__global__ __launch_bounds__(256) void ghm_wsum(
    const float* __restrict__ x, const float* __restrict__ t,
    const float* __restrict__ nbeta, float* __restrict__ psum,
    int n4, long long n_total)
{
    __shared__ float s_nb[BINS];
    if (threadIdx.x < BINS) s_nb[threadIdx.x] = nbeta[threadIdx.x];
    __syncthreads();

    const float4* __restrict__ x4 = (const float4*)x;
    const float4* __restrict__ t4 = (const float4*)t;
    int tid = blockIdx.x * blockDim.x + threadIdx.x;
    int stride = gridDim.x * blockDim.x;

    float acc = 0.0f;
    int i = tid;
    for (; i + stride < n4; i += 2 * stride) {
        float4 xa = x4[i];
        float4 ta = t4[i];
        float4 xb = x4[i + stride];
        float4 tb = t4[i + stride];
        acc += welem(xa.x, ta.x, s_nb);
        acc += welem(xa.y, ta.y, s_nb);
        acc += welem(xa.z, ta.z, s_nb);
        acc += welem(xa.w, ta.w, s_nb);
        acc += welem(xb.x, tb.x, s_nb);
        acc += welem(xb.y, tb.y, s_nb);
        acc += welem(xb.z, tb.z, s_nb);
        acc += welem(xb.w, tb.w, s_nb);
    }
    if (i < n4) {
        float4 xa = x4[i];
        float4 ta = t4[i];
        acc += welem(xa.x, ta.x, s_nb);
        acc += welem(xa.y, ta.y, s_nb);
        acc += welem(xa.z, ta.z, s_nb);
        acc += welem(xa.w, ta.w, s_nb);
    }
    long long tail_base = (long long)n4 * 4;
    long long rem = n_total - tail_base;
    if ((long long)tid < rem) {
        acc += welem(x[tail_base + tid], t[tail_base + tid], s_nb);
    }

    // wave -> block reduction (fixed tree, deterministic)
#pragma unroll
    for (int off = 32; off > 0; off >>= 1)
        acc += __shfl_down(acc, off, 64);

    __shared__ float s_s[4];
    int lane = threadIdx.x & 63;
    int wv = threadIdx.x >> 6;
    if (lane == 0) s_s[wv] = acc;
    __syncthreads();
    if (threadIdx.x == 0) {
        float bs = s_s[0] + s_s[1] + s_s[2] + s_s[3];
        if (ATOMIC) atomicAdd(psum, bs);
        else        psum[blockIdx.x] = bs;
    }
}

// Zero the tiny accumulator region (atomic fallback path only).
__global__ void ghm_zero(unsigned* pcnt, float* psum) {
    if (threadIdx.x < BINS) pcnt[threadIdx.x] = 0u;
    if (threadIdx.x == 0) psum[0] = 0.0f;
}

// Final: sum per-block partials, divide by N.
__global__ __launch_bounds__(256) void ghm_finish(
    const float* __restrict__ psum, float* __restrict__ out,
    int nblocks, float Nf)
{
    float s = 0.0f;
    for (int i = threadIdx.x; i < nblocks; i += blockDim.x) s += psum[i];
#pragma unroll
    for (int off = 32; off > 0; off >>= 1)
        s += __shfl_down(s, off, 64);
    __shared__ float s_s[4];
    int lane = threadIdx.x & 63;
    int wv = threadIdx.x >> 6;
    if (lane == 0) s_s[wv] = s;
    __syncthreads();
    if (threadIdx.x == 0)
        out[0] = (s_s[0] + s_s[1] + s_s[2] + s_s[3]) / Nf;
}

extern "C" void kernel_launch(void* const* d_in, const int* in_sizes, int n_in,
                              void* d_out, int out_size, void* d_ws, size_t ws_size,
                              hipStream_t stream) {
    const float* x = (const float*)d_in[0];
    const float* t = (const float*)d_in[1];
    float* out = (float*)d_out;

    long long N = (long long)in_sizes[0];
    int n4 = (int)(N / 4);
    const int nb = 2048;    // 8 blocks/CU x 256 thr = full residency
    float Nf = (float)N;

    size_t need = (size_t)nb * BINS * sizeof(unsigned)   // pcnt
                + (size_t)BINS * sizeof(float)           // nbeta
                + (size_t)nb * sizeof(float);            // psum

    if (ws_size >= need) {
        // Deterministic path.
        unsigned* pcnt = (unsigned*)d_ws;
        float* nbeta = (float*)(pcnt + (size_t)nb * BINS);
        float* psum = nbeta + BINS;
        ghm_count<false><<<nb, 256, 0, stream>>>(x, t, pcnt, n4, N);
        ghm_beta<<<1, 256, 0, stream>>>(pcnt, nbeta, nb, Nf);
        ghm_wsum<false><<<nb, 256, 0, stream>>>(x, t, nbeta, psum, n4, N);
        ghm_finish<<<1, 256, 0, stream>>>(psum, out, nb, Nf);
    } else {
        // Atomic fallback: ~90 B of workspace.
        unsigned* pcnt = (unsigned*)d_ws;        // [BINS]
        float* nbeta = (float*)(pcnt + BINS);    // [BINS]
        float* psum = nbeta + BINS;              // [1]
        ghm_zero<<<1, 64, 0, stream>>>(pcnt, psum);
        ghm_count<true><<<nb, 256, 0, stream>>>(x, t, pcnt, n4, N);
        ghm_beta<<<1, 256, 0, stream>>>(pcnt, nbeta, 1, Nf);
        ghm_wsum<true><<<nb, 256, 0, stream>>>(x, t, nbeta, psum, n4, N);
        ghm_finish<<<1, 256, 0, stream>>>(psum, out, 1, Nf);
    }
}

// Round 4
// 291.384 us; speedup vs baseline: 1.2781x; 1.1287x over previous
//
#include <hip/hip_runtime.h>

#define BINS 10

// bin id: reference floor(g * (10 - 1e-4)); identical fp32 ops -> bit-match
__device__ __forceinline__ int bin_of(float xx, float tt) {
    float g = fabsf(xx - tt);
    int b = (int)(g * 9.9999f);
    return b > (BINS - 1) ? (BINS - 1) : b;
}

__device__ __forceinline__ float loss_of(float xx, float tt) {
    return -(tt * __logf(xx) + (1.0f - tt) * __logf(1.0f - xx));
}

// Fused per-element accumulate. ONE v_cmp per bin is shared by:
//   - counts:  __ballot -> s_bcnt1/s_add on the SALU pipe, wave-uniform
//              wc[] lives in SGPRs (this was R3's validated trick), and
//   - sums:    v_cndmask + v_add per bin into per-lane VGPRs.
// ~3 VALU instr/bin/wave-step vs R1's ~5, and the count side is off-VALU.
// Divergence safety: every divergent caller below has a PREFIX active set
// (lane asc <=> index asc), so lane 0 participates in every ballot that
// counts anything and its wc/sum state is complete.
__device__ __forceinline__ void accum(float xx, float tt,
                                      float* __restrict__ sum,
                                      unsigned* __restrict__ wc) {
    int b = bin_of(xx, tt);
    float loss = loss_of(xx, tt);
#pragma unroll
    for (int k = 0; k < BINS; ++k) {
        bool m = (b == k);
        wc[k] += (unsigned)__popcll(__ballot(m));
        sum[k] += m ? loss : 0.0f;
    }
}

// ---------------------------------------------------------------------------
// Single data pass: per-block {bin loss-sums, bin counts}.
// 4-deep load batching: 8 independent dwordx4 (128 B/lane) issued before any
// consumption -> rolling vmcnt overlap, vs the ~2 outstanding loads the
// compiler chose in R1/R3 (VGPR_Count 16!) which latency-capped streaming
// at ~2.6 TB/s aggregate.
// ---------------------------------------------------------------------------
template <bool ATOMIC>
__global__ __launch_bounds__(256) void ghm_partial(
    const float* __restrict__ x, const float* __restrict__ t,
    float* __restrict__ psum, unsigned* __restrict__ pcnt,
    int n4, long long n_total)
{
    float sum[BINS];
    unsigned wc[BINS];
#pragma unroll
    for (int k = 0; k < BINS; ++k) { sum[k] = 0.0f; wc[k] = 0u; }

    const float4* __restrict__ x4 = (const float4*)x;
    const float4* __restrict__ t4 = (const float4*)t;
    int tid = blockIdx.x * blockDim.x + threadIdx.x;
    int stride = gridDim.x * blockDim.x;

    int i = tid;
    for (; i + 3 * stride < n4; i += 4 * stride) {
        // issue all 8 loads first (independent addresses)
        float4 xa = x4[i];
        float4 xb = x4[i + stride];
        float4 xc = x4[i + 2 * stride];
        float4 xd = x4[i + 3 * stride];
        float4 ta = t4[i];
        float4 tb = t4[i + stride];
        float4 tc = t4[i + 2 * stride];
        float4 td = t4[i + 3 * stride];
        // consume in load order -> compiler can use counted vmcnt waits
        accum(xa.x, ta.x, sum, wc);
        accum(xa.y, ta.y, sum, wc);
        accum(xa.z, ta.z, sum, wc);
        accum(xa.w, ta.w, sum, wc);
        accum(xb.x, tb.x, sum, wc);
        accum(xb.y, tb.y, sum, wc);
        accum(xb.z, tb.z, sum, wc);
        accum(xb.w, tb.w, sum, wc);
        accum(xc.x, tc.x, sum, wc);
        accum(xc.y, tc.y, sum, wc);
        accum(xc.z, tc.z, sum, wc);
        accum(xc.w, tc.w, sum, wc);
        accum(xd.x, td.x, sum, wc);
        accum(xd.y, td.y, sum, wc);
        accum(xd.z, td.z, sum, wc);
        accum(xd.w, td.w, sum, wc);
    }
    for (; i < n4; i += stride) {       // leftover strided float4s (prefix-active)
        float4 xa = x4[i];
        float4 ta = t4[i];
        accum(xa.x, ta.x, sum, wc);
        accum(xa.y, ta.y, sum, wc);
        accum(xa.z, ta.z, sum, wc);
        accum(xa.w, ta.w, sum, wc);
    }
    long long tail_base = (long long)n4 * 4;
    long long rem = n_total - tail_base;
    if ((long long)tid < rem) {         // scalar tail (prefix-active)
        accum(x[tail_base + tid], t[tail_base + tid], sum, wc);
    }

    // wave(64) shuffle reduction of the 10 per-lane sums (counts are already
    // wave-uniform in SGPRs -> no reduction needed)
#pragma unroll
    for (int k = 0; k < BINS; ++k) {
#pragma unroll
        for (int off = 32; off > 0; off >>= 1)
            sum[k] += __shfl_down(sum[k], off, 64);
    }

    __shared__ float s_sum[4][BINS];
    __shared__ unsigned s_cnt[4][BINS];
    int lane = threadIdx.x & 63;
    int wv = threadIdx.x >> 6;
    if (lane == 0) {
#pragma unroll
        for (int k = 0; k < BINS; ++k) { s_sum[wv][k] = sum[k]; s_cnt[wv][k] = wc[k]; }
    }
    __syncthreads();
    if (threadIdx.x < BINS) {
        float s = 0.0f;
        unsigned c = 0u;
#pragma unroll
        for (int w = 0; w < 4; ++w) { s += s_sum[w][threadIdx.x]; c += s_cnt[w][threadIdx.x]; }
        if (ATOMIC) {
            atomicAdd(&psum[threadIdx.x], s);
            atomicAdd(&pcnt[threadIdx.x], c);
        } else {
            psum[(size_t)blockIdx.x * BINS + threadIdx.x] = s;
            pcnt[(size_t)blockIdx.x * BINS + threadIdx.x] = c;
        }
    }
}

// Zero the tiny accumulator region (atomic fallback path only).
__global__ void ghm_zero(float* psum, unsigned* pcnt) {
    if (threadIdx.x < BINS) { psum[threadIdx.x] = 0.0f; pcnt[threadIdx.x] = 0u; }
}

// Single-block finalize: reduce per-block partials, compute beta, weighted sum.
// (verbatim from R1 -- verified absmax 0.0)
__global__ __launch_bounds__(256) void ghm_final(
    const float* __restrict__ psum, const unsigned* __restrict__ pcnt,
    float* __restrict__ out, int nblocks, float Nf)
{
    float sum[BINS];
    unsigned cnt[BINS];
#pragma unroll
    for (int k = 0; k < BINS; ++k) { sum[k] = 0.0f; cnt[k] = 0u; }

    for (int i = threadIdx.x; i < nblocks; i += blockDim.x) {
#pragma unroll
        for (int k = 0; k < BINS; ++k) {
            sum[k] += psum[(size_t)i * BINS + k];
            cnt[k] += pcnt[(size_t)i * BINS + k];
        }
    }

#pragma unroll
    for (int k = 0; k < BINS; ++k) {
#pragma unroll
        for (int off = 32; off > 0; off >>= 1) {
            sum[k] += __shfl_down(sum[k], off, 64);
            cnt[k] += (unsigned)__shfl_down((int)cnt[k], off, 64);
        }
    }

    __shared__ float s_sum[4][BINS];
    __shared__ unsigned s_cnt[4][BINS];
    int lane = threadIdx.x & 63;
    int wv = threadIdx.x >> 6;
    if (lane == 0) {
#pragma unroll
        for (int k = 0; k < BINS; ++k) { s_sum[wv][k] = sum[k]; s_cnt[wv][k] = cnt[k]; }
    }
    __syncthreads();

    if (threadIdx.x == 0) {
        float tot_s[BINS];
        unsigned tot_c[BINS];
#pragma unroll
        for (int k = 0; k < BINS; ++k) {
            float s = 0.0f;
            unsigned c = 0u;
#pragma unroll
            for (int w = 0; w < 4; ++w) { s += s_sum[w][k]; c += s_cnt[w][k]; }
            tot_s[k] = s;
            tot_c[k] = c;
        }
        float nonempty = 0.0f;
#pragma unroll
        for (int k = 0; k < BINS; ++k) nonempty += (tot_c[k] > 0u) ? 1.0f : 0.0f;
        float total = 0.0f;
#pragma unroll
        for (int k = 0; k < BINS; ++k) {
            float gd = (float)tot_c[k] * nonempty;
            gd = gd < 1.0f ? 1.0f : gd;      // clip(gd, 1, None)
            float beta = Nf / gd;
            total += tot_s[k] * beta;
        }
        out[0] = total / Nf;   // mean
    }
}

extern "C" void kernel_launch(void* const* d_in, const int* in_sizes, int n_in,
                              void* d_out, int out_size, void* d_ws, size_t ws_size,
                              hipStream_t stream) {
    const float* x = (const float*)d_in[0];
    const float* t = (const float*)d_in[1];
    float* out = (float*)d_out;

    long long N = (long long)in_sizes[0];
    int n4 = (int)(N / 4);

    // 2048 blocks x 256 thr = 8192 waves = 32 waves/CU on 256 CUs.
    const int nblocks = 2048;
    const size_t per_block = (size_t)BINS * (sizeof(float) + sizeof(unsigned)); // 80 B

    if (ws_size >= (size_t)nblocks * per_block) {
        // Deterministic two-stage reduction (preferred).
        float* psum = (float*)d_ws;
        unsigned* pcnt = (unsigned*)(psum + (size_t)nblocks * BINS);
        ghm_partial<false><<<nblocks, 256, 0, stream>>>(x, t, psum, pcnt, n4, N);
        ghm_final<<<1, 256, 0, stream>>>(psum, pcnt, out, nblocks, (float)N);
    } else {
        // Atomic fallback: 80 B of workspace.
        float* psum = (float*)d_ws;
        unsigned* pcnt = (unsigned*)(psum + BINS);
        ghm_zero<<<1, 64, 0, stream>>>(psum, pcnt);
        ghm_partial<true><<<nblocks, 256, 0, stream>>>(x, t, psum, pcnt, n4, N);
        ghm_final<<<1, 256, 0, stream>>>(psum, pcnt, out, 1, (float)N);
    }
}